// Round 13
// baseline (359.267 us; speedup 1.0000x reference)
//
#include <hip/hip_runtime.h>
#include <hip/hip_fp16.h>
#include <type_traits>

#define NN 10000
#define EE 160000

typedef _Float16 half8 __attribute__((ext_vector_type(8)));
typedef float    f32x4 __attribute__((ext_vector_type(4)));

// ---------------------------------------------------------------------------
// Node phase:
//  pre : Xt[(n,ij)][c] fp16  <- X[n][c][ij] f32      (pack/transpose)
//  gemm: Xp[(n,ij)][o] = sum_c Xt * Wp[o][c] + bp[o] (k_gemm_pipe)
//  post: per (n,o): norm over 9 ij, decompose -> Xn[n][o][ij], D1[n][10][128]
// ---------------------------------------------------------------------------
__global__ __launch_bounds__(256) void k_node_pre(
    const float* __restrict__ X, _Float16* __restrict__ Xt)
{
  __shared__ float Xl[4*1152];
  const int n0 = blockIdx.x * 4;
  const int t = threadIdx.x;
  const float* src = X + (size_t)n0*1152;
  #pragma unroll
  for (int idx = t; idx < 4*1152; idx += 256) Xl[idx] = src[idx];
  __syncthreads();
  _Float16* dst = Xt + (size_t)n0*1152;
  #pragma unroll
  for (int idx = t; idx < 4*1152; idx += 256) {
    int node = idx / 1152, rem = idx - node*1152;
    int ij = rem >> 7, c = rem & 127;
    dst[idx] = (_Float16)Xl[node*1152 + c*9 + ij];   // stride-9 LDS: odd -> conflict-free
  }
}

__global__ __launch_bounds__(256) void k_node_post(
    const _Float16* __restrict__ Xp,
    __half* __restrict__ Xn, __half* __restrict__ D1)
{
  int idx = blockIdx.x*256 + threadIdx.x;
  int n = idx >> 7, o = idx & 127;
  float m[9], ss = 0.f;
  #pragma unroll
  for (int ij = 0; ij < 9; ++ij) {
    m[ij] = (float)Xp[((size_t)n*9 + ij)*128 + o];   // coalesced across o
    ss += m[ij]*m[ij];
  }
  ss = fmaxf(ss, 0.01f);
  float inv = 1.f / (ss + 1.f);
  #pragma unroll
  for (int ij = 0; ij < 9; ++ij) m[ij] *= inv;
  __half* xo = &Xn[(size_t)n*1152 + o*9];
  #pragma unroll
  for (int ij = 0; ij < 9; ++ij) xo[ij] = __float2half(m[ij]);
  float lam = (m[0]+m[4]+m[8]) * (1.f/3.f);
  __half* Dn = &D1[(size_t)n*1280];
  Dn[0*128+o] = __float2half(lam);
  Dn[1*128+o] = __float2half(0.5f*(m[1]-m[3]));
  Dn[2*128+o] = __float2half(0.5f*(m[2]-m[6]));
  Dn[3*128+o] = __float2half(0.5f*(m[5]-m[7]));
  Dn[4*128+o] = __float2half(m[0]-lam);
  Dn[5*128+o] = __float2half(0.5f*(m[1]+m[3]));
  Dn[6*128+o] = __float2half(0.5f*(m[2]+m[6]));
  Dn[7*128+o] = __float2half(m[4]-lam);
  Dn[8*128+o] = __float2half(0.5f*(m[5]+m[7]));
  Dn[9*128+o] = __float2half(m[8]-lam);
}

// ---------------------------------------------------------------------------
// Prep (ONE launch): frag-linear fp16 pack of Wp, Ws1, Ws2, Wt0..Wt5 + zero cur_
//   Wfl[((kc*(N/16) + nf)*64 + lane)*8 + j] = W[nf*16+(lane&15)][kc*32+(lane>>4)*8+j]
// ---------------------------------------------------------------------------
__device__ __forceinline__ void wprep_one(
    const float* __restrict__ W, _Float16* __restrict__ Wfl, int N, int K, int u)
{
  int lane = u & 63, rest = u >> 6;
  int nfTotal = N >> 4;
  int nf = rest % nfTotal, kc = rest / nfTotal;
  int n = nf*16 + (lane & 15);
  int k = kc*32 + (lane >> 4)*8;
  const float* src = W + (size_t)n*K + k;
  half8 hv;
  #pragma unroll
  for (int j = 0; j < 8; ++j) hv[j] = (_Float16)src[j];
  *reinterpret_cast<half8*>(Wfl + (size_t)u*8) = hv;
}
__global__ __launch_bounds__(256) void k_prep(
    const float* __restrict__ Wp, const float* __restrict__ Ws1,
    const float* __restrict__ Ws2,
    const float* __restrict__ Wt0, const float* __restrict__ Wt1,
    const float* __restrict__ Wt2, const float* __restrict__ Wt3,
    const float* __restrict__ Wt4, const float* __restrict__ Wt5,
    _Float16* __restrict__ W0fl, _Float16* __restrict__ W1fl,
    _Float16* __restrict__ W2fl, _Float16* __restrict__ Wtfl,
    int* __restrict__ cur)
{
  int u = blockIdx.x*256 + threadIdx.x;
  if (u < NN) cur[u] = 0;
  if (u < 2048)        wprep_one(Wp,  W0fl, 128, 128, u);
  else if (u < 6144)   wprep_one(Ws1, W1fl, 256, 128, u - 2048);
  else if (u < 18432)  wprep_one(Ws2, W2fl, 384, 256, u - 6144);
  else if (u < 30720) {
    int v = u - 18432;
    int wi = v >> 11, r = v & 2047;
    const float* Wt = (wi==0)?Wt0:(wi==1)?Wt1:(wi==2)?Wt2:(wi==3)?Wt3:(wi==4)?Wt4:Wt5;
    wprep_one(Wt, Wtfl + wi*16384, 128, 128, r);
  }
}

// ---------------------------------------------------------------------------
// Pipelined MFMA GEMM (m97 structure): C[m][n] = post(sum_k A[m][k]*W[n][k]+b[n])
//   - BM=128, BN=128, BK=32, 4 waves; wave owns 32 rows x 128 cols (acc[2][8])
//   - A and W double-buffered via global_load_lds width-16 DMA
//   - A LDS seg pre-swizzled seg^(row&3) at source; read seg = lq^(lr&3)
//   - rowmap (optional): output row permutation (CSR-ordered write)
//   - PSEL: blockIdx.z = p in 0..9: W = Wfl + widx*16384 (widx = 0/1/2 by p),
//     A,C col-offset p*128 (lda/ldc = 1280); nTiles must be 1
// ---------------------------------------------------------------------------
template<int KT, bool ACT, bool CUT, bool PSEL>
__global__ __launch_bounds__(256, 4) void k_gemm_pipe(
    const _Float16* __restrict__ A, int lda,
    const _Float16* __restrict__ Wfl,
    const float* __restrict__ bias, const float* __restrict__ cw,
    const int* __restrict__ rowmap,
    _Float16* __restrict__ C, int ldc,
    int M, int nTiles)
{
  constexpr int NC = KT / 32;
  __shared__ _Float16 Abuf[2][128*32];
  __shared__ _Float16 Wbuf[2][128*32];
  const int t = threadIdx.x;
  const int nfTotal = nTiles * 8;

  int nwg = gridDim.x, bid = blockIdx.x;
  int q = nwg >> 3, rr = nwg & 7;
  int xcd = bid & 7, ii = bid >> 3;
  int swz = (xcd < rr) ? xcd*(q+1) + ii : rr*(q+1) + (xcd-rr)*q + ii;
  int nt = swz % nTiles, mt = swz / nTiles;
  const int n0 = nt * 128, m0 = mt * 128;

  const _Float16* Wb_ = Wfl;
  int coff = 0;
  if (PSEL) {
    int p = blockIdx.z;
    int widx = (p == 0) ? 0 : (p < 4 ? 1 : 2);
    Wb_ = Wfl + widx*16384;
    coff = p * 128;
  }

  auto stage = [&](int d, int kc) {
    #pragma unroll
    for (int i = 0; i < 2; ++i) {
      int u = t + i*256;
      int row = u >> 2, seg = u & 3;
      int gm = m0 + row; if (gm > M-1) gm = M-1;
      const _Float16* gp = A + (size_t)gm*lda + coff + kc*32 + ((seg ^ (row & 3)) << 3);
      __builtin_amdgcn_global_load_lds(
          (const __attribute__((address_space(1))) _Float16*)gp,
          (__attribute__((address_space(3))) _Float16*)(&Abuf[d][u*8]), 16, 0, 0);
    }
    const _Float16* wp = Wb_ + (((size_t)kc*nfTotal + nt*8) << 9);
    #pragma unroll
    for (int i = 0; i < 2; ++i) {
      int u = t + i*256;
      __builtin_amdgcn_global_load_lds(
          (const __attribute__((address_space(1))) _Float16*)(wp + u*8),
          (__attribute__((address_space(3))) _Float16*)(&Wbuf[d][u*8]), 16, 0, 0);
    }
  };

  const int wave = t >> 6, lane = t & 63;
  const int lr = lane & 15, lq = lane >> 4;
  const int wrow = wave * 32;
  const int aoff = (lq ^ (lr & 3)) << 3;

  f32x4 acc[2][8] = {};

  stage(0, 0);
  __syncthreads();
  int cur = 0;
  for (int kc = 0; kc < NC; ++kc) {
    if (kc + 1 < NC) stage(cur ^ 1, kc + 1);
    const _Float16* ab = &Abuf[cur][0];
    const _Float16* wb = &Wbuf[cur][0];
    half8 a0 = *reinterpret_cast<const half8*>(ab + (wrow + lr)*32 + aoff);
    half8 a1 = *reinterpret_cast<const half8*>(ab + (wrow + 16 + lr)*32 + aoff);
    #pragma unroll
    for (int c = 0; c < 8; ++c) {
      half8 b = *reinterpret_cast<const half8*>(wb + c*512 + lane*8);
      acc[0][c] = __builtin_amdgcn_mfma_f32_16x16x32_f16(a0, b, acc[0][c], 0, 0, 0);
      acc[1][c] = __builtin_amdgcn_mfma_f32_16x16x32_f16(a1, b, acc[1][c], 0, 0, 0);
    }
    if (kc + 1 < NC) { __syncthreads(); cur ^= 1; }
  }

  float bvv[8];
  #pragma unroll
  for (int c = 0; c < 8; ++c) bvv[c] = bias ? bias[n0 + c*16 + lr] : 0.f;
  #pragma unroll
  for (int r = 0; r < 2; ++r) {
    #pragma unroll
    for (int j = 0; j < 4; ++j) {
      int gm = m0 + wrow + r*16 + lq*4 + j;   // C/D: col=lane&15, row=(lane>>4)*4+reg
      if (gm >= M) continue;
      float Cf = 1.f;
      if (CUT) {
        float wv = cw[gm];
        Cf = (wv < 5.f) ? 0.5f*(__cosf(wv*0.62831853071795864769f) + 1.f) : 0.f;
      }
      int orow = rowmap ? rowmap[gm] : gm;
      _Float16* crow = C + (size_t)orow*ldc + coff + n0;
      #pragma unroll
      for (int c = 0; c < 8; ++c) {
        float v = acc[r][c][j] + bvv[c];
        if (ACT) v = v / (1.f + __expf(-v));   // silu
        if (CUT) v *= Cf;
        crow[c*16 + lr] = (_Float16)v;
      }
    }
  }
}

// ---------------------------------------------------------------------------
// MFMA GEMM (non-pipelined; used for G1: f32 A, K=32):
//   BM=256, BN=64; W staged fp32->fp16 fragment-linear LDS (conflict-free)
// ---------------------------------------------------------------------------
template<typename TA, int KT, bool ACT>
__global__ __launch_bounds__(256) void k_gemm_mfma(
    const TA* __restrict__ A, int lda,
    const float* __restrict__ W0,
    const float* __restrict__ bias,
    _Float16* __restrict__ C, int ldc,
    int M, int nTiles)
{
  constexpr int NFRAG = (KT/32)*4;
  __shared__ _Float16 Bs[NFRAG*64*8];
  const int t = threadIdx.x;

  int nwg = gridDim.x;
  int bid = blockIdx.x;
  int q = nwg >> 3, rr = nwg & 7;
  int xcd = bid & 7, ii = bid >> 3;
  int swz = (xcd < rr) ? xcd*(q+1) + ii : rr*(q+1) + (xcd-rr)*q + ii;
  int nt = swz % nTiles;
  int mt = swz / nTiles;

  const float* W = W0;
  const int n0 = nt * 64;
  const int m0 = mt * 256;

  #pragma unroll
  for (int u = t; u < NFRAG*64; u += 256) {
    int g = u >> 6, lu = u & 63;
    int lru = lu & 15, lqu = lu >> 4;
    int nn = (g & 3)*16 + lru;
    int kk = (g >> 2)*32 + lqu*8;
    const float* wp = &W[(size_t)(n0 + nn)*KT + kk];
    f32x4 w0 = *reinterpret_cast<const f32x4*>(wp);
    f32x4 w1 = *reinterpret_cast<const f32x4*>(wp + 4);
    half8 hv;
    #pragma unroll
    for (int j = 0; j < 4; ++j) { hv[j] = (_Float16)w0[j]; hv[4+j] = (_Float16)w1[j]; }
    *reinterpret_cast<half8*>(&Bs[u*8]) = hv;
  }
  __syncthreads();

  const int wave = t >> 6, lane = t & 63;
  const int lr = lane & 15, lq = lane >> 4;
  const int rowBase = m0 + wave*64;
  const int kBase = lq*8;

  const TA* aptr[4];
  #pragma unroll
  for (int r = 0; r < 4; ++r) {
    int gm = rowBase + r*16 + lr;
    if (gm > M-1) gm = M-1;
    aptr[r] = A + (size_t)gm*lda + kBase;
  }

  f32x4 acc[4][4] = {};
  #pragma unroll
  for (int k0 = 0; k0 < KT; k0 += 32) {
    half8 b[4];
    #pragma unroll
    for (int c = 0; c < 4; ++c)
      b[c] = *reinterpret_cast<const half8*>(&Bs[(((k0>>5)<<2) + c)*512 + lane*8]);
    half8 a[4];
    #pragma unroll
    for (int r = 0; r < 4; ++r) {
      const TA* ap = aptr[r] + k0;
      if constexpr (std::is_same<TA, float>::value) {
        f32x4 u0 = *reinterpret_cast<const f32x4*>(ap);
        f32x4 u1 = *reinterpret_cast<const f32x4*>(ap + 4);
        half8 av;
        #pragma unroll
        for (int j = 0; j < 4; ++j) { av[j] = (_Float16)u0[j]; av[4+j] = (_Float16)u1[j]; }
        a[r] = av;
      } else {
        a[r] = *reinterpret_cast<const half8*>(ap);
      }
    }
    #pragma unroll
    for (int r = 0; r < 4; ++r)
      #pragma unroll
      for (int c = 0; c < 4; ++c)
        acc[r][c] = __builtin_amdgcn_mfma_f32_16x16x32_f16(a[r], b[c], acc[r][c], 0, 0, 0);
  }

  float bvv[4];
  #pragma unroll
  for (int c = 0; c < 4; ++c)
    bvv[c] = bias ? bias[n0 + c*16 + lr] : 0.f;
  #pragma unroll
  for (int r = 0; r < 4; ++r) {
    #pragma unroll
    for (int j = 0; j < 4; ++j) {
      int gm = rowBase + r*16 + lq*4 + j;
      if (gm >= M) continue;
      _Float16* crow = C + (size_t)gm*ldc + n0;
      #pragma unroll
      for (int c = 0; c < 4; ++c) {
        float v = acc[r][c][j] + bvv[c];
        if (ACT) v = v / (1.f + __expf(-v));
        crow[c*16 + lr] = (_Float16)v;
      }
    }
  }
}

// ---------------------------------------------------------------------------
// CSR build over src. Scatter emits inv[e]=pos, dst_s[pos]=dst[e], eid_s[pos]=e.
// ---------------------------------------------------------------------------
__global__ void k_hist(const int* __restrict__ src, int* __restrict__ cnt) {
  int e = blockIdx.x*256 + threadIdx.x;
  if (e < EE) atomicAdd(&cnt[src[e]], 1);
}
// scan + degree-descending counting sort (both single-block -> merged)
__global__ __launch_bounds__(1024) void k_scan_sort(
    const int* __restrict__ cnt, int* __restrict__ off,
    int* __restrict__ cur, int* __restrict__ perm)
{
  __shared__ int s[1024];
  __shared__ int carry;
  __shared__ int bins[64];
  __shared__ int basep[64];
  int t = threadIdx.x;
  if (t == 0) carry = 0;
  __syncthreads();
  for (int base = 0; base < NN; base += 1024) {
    int i = base + t;
    int v = (i < NN) ? cnt[i] : 0;
    s[t] = v; __syncthreads();
    for (int d = 1; d < 1024; d <<= 1) {
      int x = (t >= d) ? s[t-d] : 0; __syncthreads();
      s[t] += x; __syncthreads();
    }
    int incl = s[t];
    int total = s[1023];
    int excl = incl - v + carry;
    if (i < NN) { off[i] = excl; cur[i] = excl; }
    __syncthreads();
    if (t == 0) carry += total;
    __syncthreads();
  }
  if (t == 0) off[NN] = carry;
  if (t < 64) bins[t] = 0;
  __syncthreads();
  for (int i = t; i < NN; i += 1024) {
    int d = off[i+1] - off[i];
    int b = 63 - (d > 63 ? 63 : d);
    atomicAdd(&bins[b], 1);
  }
  __syncthreads();
  if (t == 0) {
    int acc = 0;
    for (int b = 0; b < 64; ++b) { basep[b] = acc; acc += bins[b]; }
  }
  __syncthreads();
  for (int i = t; i < NN; i += 1024) {
    int d = off[i+1] - off[i];
    int b = 63 - (d > 63 ? 63 : d);
    int pos = atomicAdd(&basep[b], 1);
    perm[pos] = i;
  }
}
__global__ void k_scatter(const int* __restrict__ src, const int* __restrict__ dst,
                          int* __restrict__ cur,
                          int* __restrict__ inv, int* __restrict__ dst_s,
                          int* __restrict__ eid_s) {
  int e = blockIdx.x*256 + threadIdx.x;
  if (e < EE) {
    int pos = atomicAdd(&cur[src[e]], 1);
    inv[e] = pos;
    dst_s[pos] = dst[e];
    eid_s[pos] = e;
  }
}

// ---------------------------------------------------------------------------
// Per-node dst-sort (64-edge chunks): sorts each node's CSR segment by dst via
// 64-lane bitonic shfl network on packed keys (dst<<18 | eid), then rewrites
// dst_s and inv consistently. Purpose: concurrently-executing msgbr waves all
// walk dst in ascending order -> T1 gather gains cross-wave L2 temporal
// locality. Any chunk permutation is numerically valid (commutative sum) and
// this makes edge order deterministic (eid tiebreak).
// ---------------------------------------------------------------------------
__global__ __launch_bounds__(256) void k_dstsort(
    const int* __restrict__ off, int* __restrict__ dst_s,
    const int* __restrict__ eid_s, int* __restrict__ inv)
{
  const int t = threadIdx.x;
  const int l = t & 63;
  const int wv = t >> 6;
  const int n = blockIdx.x*4 + wv;
  if (n >= NN) return;
  const int e0 = off[n], e1 = off[n+1];
  for (int cs = e0; cs < e1; cs += 64) {
    int m = e1 - cs; if (m > 64) m = 64;
    unsigned key = 0xFFFFFFFFu;
    if (l < m) {
      unsigned d = (unsigned)dst_s[cs + l];
      unsigned e = (unsigned)eid_s[cs + l];
      key = (d << 18) | e;
    }
    // full 64-lane bitonic sort (ascending)
    #pragma unroll
    for (int k = 2; k <= 64; k <<= 1) {
      #pragma unroll
      for (int j = k >> 1; j > 0; j >>= 1) {
        unsigned other = (unsigned)__shfl_xor((int)key, j, 64);
        bool asc = ((l & k) == 0);
        bool takeMin = (((l & j) == 0) == asc);
        unsigned mn = key < other ? key : other;
        unsigned mx = key < other ? other : key;
        key = takeMin ? mn : mx;
      }
    }
    if (l < m) {
      int d = (int)(key >> 18);
      int e = (int)(key & 0x3FFFFu);
      dst_s[cs + l] = d;
      inv[e] = cs + l;
    }
  }
}

// ---------------------------------------------------------------------------
// Fused message + bracket, degree-balanced, dst-prefetched, dst-ordered:
//  - 4 nodes/block via perm, 1 wave/node, lane l owns o-pair (2l, 2l+1)
//  - dst indices batch-prefetched (wave-load + v_readlane)
//  - msg in regs (f32); then B = M*Y+Y*M, decompose, /(tnorm+1)
//  - ea stream non-temporal; D2 buffer != T1
// ---------------------------------------------------------------------------
__device__ __forceinline__ void bracket10(
    const float* __restrict__ M, const float* __restrict__ Y,
    float* __restrict__ D)
{
  float Mm[9], Ym[9];
  Mm[0]=M[0]+M[4]; Mm[1]=M[1]+M[5]; Mm[2]=M[2]+M[6];
  Mm[3]=M[5]-M[1]; Mm[4]=M[0]+M[7]; Mm[5]=M[3]+M[8];
  Mm[6]=M[6]-M[2]; Mm[7]=M[8]-M[3]; Mm[8]=M[0]+M[9];
  Ym[0]=Y[0]+Y[4]; Ym[1]=Y[1]+Y[5]; Ym[2]=Y[2]+Y[6];
  Ym[3]=Y[5]-Y[1]; Ym[4]=Y[0]+Y[7]; Ym[5]=Y[3]+Y[8];
  Ym[6]=Y[6]-Y[2]; Ym[7]=Y[8]-Y[3]; Ym[8]=Y[0]+Y[9];
  float B[9];
  #pragma unroll
  for (int i = 0; i < 3; ++i)
    #pragma unroll
    for (int j = 0; j < 3; ++j) {
      float s = 0.f;
      #pragma unroll
      for (int k = 0; k < 3; ++k)
        s += Mm[i*3+k]*Ym[k*3+j] + Ym[i*3+k]*Mm[k*3+j];
      B[i*3+j] = s;
    }
  float lamb = (B[0]+B[4]+B[8]) * (1.f/3.f);
  float ss = 0.f;
  #pragma unroll
  for (int qq = 0; qq < 9; ++qq) ss += B[qq]*B[qq];
  float inv = 1.f / (fmaxf(ss, 0.01f) + 1.f);
  D[0] = lamb*inv;
  D[1] = 0.5f*(B[1]-B[3])*inv;
  D[2] = 0.5f*(B[2]-B[6])*inv;
  D[3] = 0.5f*(B[5]-B[7])*inv;
  D[4] = (B[0]-lamb)*inv;
  D[5] = 0.5f*(B[1]+B[3])*inv;
  D[6] = 0.5f*(B[2]+B[6])*inv;
  D[7] = (B[4]-lamb)*inv;
  D[8] = 0.5f*(B[5]+B[7])*inv;
  D[9] = (B[8]-lamb)*inv;
}

__device__ __forceinline__ float2 ld_nt_h2(const void* p) {
  unsigned int u = __builtin_nontemporal_load((const unsigned int*)p);
  return __half22float2(__builtin_bit_cast(__half2, u));
}

__global__ __launch_bounds__(256) void k_msgbr(
    const __half* __restrict__ ea_s, const __half* __restrict__ T1,
    const int* __restrict__ dst_s, const int* __restrict__ off,
    const int* __restrict__ perm, __half* __restrict__ D2)
{
  const int t = threadIdx.x;
  const int l = t & 63;
  const int wv = __builtin_amdgcn_readfirstlane(t >> 6);
  const int n = __builtin_amdgcn_readfirstlane(perm[blockIdx.x*4 + wv]);
  const int e0 = __builtin_amdgcn_readfirstlane(off[n]);
  const int e1 = __builtin_amdgcn_readfirstlane(off[n+1]);

  float a0[10] = {}, a1[10] = {};   // msg for o0=2l and o1=2l+1

  for (int be = e0; be < e1; be += 64) {
    // batch-prefetch up to 64 dst indices: lane l holds dst of edge be+l
    int my = be + l; if (my > e1-1) my = e1-1;
    int vd = dst_s[my];
    int hi = (be + 64 < e1) ? be + 64 : e1;

    auto edge = [&](int ii) {
      int d = __builtin_amdgcn_readlane(vd, ii - be);   // uniform idx, no mem op
      const __half2* fe = (const __half2*)(ea_s + (size_t)ii*384 + 6*l);
      float2 q0 = ld_nt_h2(fe);       // f0(o0), f1(o0)
      float2 q1 = ld_nt_h2(fe + 1);   // f2(o0), f0(o1)
      float2 q2 = ld_nt_h2(fe + 2);   // f1(o1), f2(o1)
      const __half2* Td = (const __half2*)(T1 + (size_t)d*1280) + l;
      float2 tc;
      tc = __half22float2(Td[0]);    a0[0] += q0.x*tc.x; a1[0] += q1.y*tc.y;
      tc = __half22float2(Td[64]);   a0[1] += q0.y*tc.x; a1[1] += q2.x*tc.y;
      tc = __half22float2(Td[128]);  a0[2] += q0.y*tc.x; a1[2] += q2.x*tc.y;
      tc = __half22float2(Td[192]);  a0[3] += q0.y*tc.x; a1[3] += q2.x*tc.y;
      #pragma unroll
      for (int c = 4; c < 10; ++c) {
        tc = __half22float2(Td[c*64]);
        a0[c] += q1.x*tc.x; a1[c] += q2.y*tc.y;
      }
    };
    int ii = be;
    for (; ii + 4 <= hi; ii += 4) { edge(ii); edge(ii+1); edge(ii+2); edge(ii+3); }
    for (; ii < hi; ++ii) edge(ii);
  }

  // own node's Y row
  const __half2* Yd = (const __half2*)(T1 + (size_t)n*1280) + l;
  float y0[10], y1[10];
  #pragma unroll
  for (int c = 0; c < 10; ++c) {
    float2 yc = __half22float2(Yd[c*64]);
    y0[c] = yc.x; y1[c] = yc.y;
  }
  float d0[10], d1[10];
  bracket10(a0, y0, d0);
  bracket10(a1, y1, d1);
  __half2* Dn = (__half2*)(D2 + (size_t)n*1280) + l;
  #pragma unroll
  for (int c = 0; c < 10; ++c)
    Dn[c*64] = __floats2half2_rn(d0[c], d1[c]);
}

// ---------------------------------------------------------------------------
// Final: out = Xn + reconstruct(Tb)
// ---------------------------------------------------------------------------
__global__ __launch_bounds__(256) void k_final(
    const __half* __restrict__ Xn, const __half* __restrict__ Tb,
    float* __restrict__ out)
{
  int idx = blockIdx.x*256 + threadIdx.x;
  int n = idx >> 7, o = idx & 127;
  const __half* Tc = &Tb[(size_t)n*1280 + o];
  float lam=(float)Tc[0], a0=(float)Tc[128], a1=(float)Tc[256], a2=(float)Tc[384];
  float s00=(float)Tc[512], s01=(float)Tc[640], s02=(float)Tc[768];
  float s11=(float)Tc[896], s12=(float)Tc[1024], s22=(float)Tc[1152];
  const __half* xc = &Xn[(size_t)n*1152 + o*9];
  float* oc = &out[(size_t)n*1152 + o*9];
  oc[0] = (float)xc[0] + lam + s00;
  oc[1] = (float)xc[1] + a0  + s01;
  oc[2] = (float)xc[2] + a1  + s02;
  oc[3] = (float)xc[3] - a0  + s01;
  oc[4] = (float)xc[4] + lam + s11;
  oc[5] = (float)xc[5] + a2  + s12;
  oc[6] = (float)xc[6] - a1  + s02;
  oc[7] = (float)xc[7] - a2  + s12;
  oc[8] = (float)xc[8] + lam + s22;
}

// ---------------------------------------------------------------------------
extern "C" void kernel_launch(void* const* d_in, const int* in_sizes, int n_in,
                              void* d_out, int out_size, void* d_ws, size_t ws_size,
                              hipStream_t stream)
{
  const float* X     = (const float*)d_in[0];
  const float* ew    = (const float*)d_in[1];
  const float* eattr = (const float*)d_in[2];
  const float* Wp    = (const float*)d_in[3];
  const float* bp    = (const float*)d_in[4];
  const float* Ws0   = (const float*)d_in[5];
  const float* bs0   = (const float*)d_in[6];
  const float* Ws1   = (const float*)d_in[7];
  const float* bs1   = (const float*)d_in[8];
  const float* Ws2   = (const float*)d_in[9];
  const float* bs2   = (const float*)d_in[10];
  const int*   eidx  = (const int*)d_in[11];
  const float* Wt0   = (const float*)d_in[12];
  const float* Wt1   = (const float*)d_in[13];
  const float* Wt2   = (const float*)d_in[14];
  const float* Wt3   = (const float*)d_in[15];
  const float* Wt4   = (const float*)d_in[16];
  const float* Wt5   = (const float*)d_in[17];
  float* out = (float*)d_out;

  // Packed lifetime-aliased layout, peak 255,973,440 B:
  //  A [0,          23,040,000)  Xn fp16                  [node_post -> final]
  //  B [23,040,000, 48,640,000)  T1 fp16 [K2 -> msgbr] -> Tb [K4 -> final]
  //  C [48,640,000, 130,560,000) {D1 | Xt | Xp} -> h1 -> D2 [msgbr -> K4]
  //  D [130,560,000,253,440,000) h0 -> ea_s               (122.88 MB)
  //  csr [253,440,000, 254,801,920)  off, cur, inv, dst_s
  //  Wfl [254,801,920, 255,096,832)  frag-linear fp16 Wp, Ws1, Ws2
  //  perm [255,096,832, 255,136,832); Wtfl [255,136,832, 255,333,440)
  //  eid_s [255,333,440, 255,973,440)
  const size_t NEED = 255973440;
  if (ws_size < NEED) return;   // diagnostic: poison-fail instead of fault

  char* base = (char*)d_ws;
  __half*   Xn  = (__half*)(base);
  __half*   T1  = (__half*)(base + 23040000);
  __half*   Tb  = (__half*)(base + 23040000);          // reuses T1 (dead after msgbr)
  __half*   D1  = (__half*)(base + 48640000);          // 25.6 MB [node_post -> K2]
  _Float16* Xt  = (_Float16*)(base + 74240000);        // 23.04 MB [pre -> gemm]
  _Float16* Xp  = (_Float16*)(base + 97280000);        // 23.04 MB [gemm -> post]
  __half*   h1  = (__half*)(base + 48640000);
  __half*   D2  = (__half*)(base + 48640000);          // msgbr output [-> K4]
  __half*   h0  = (__half*)(base + 130560000);
  __half*   ea  = (__half*)(base + 130560000);
  int* off_  = (int*)(base + 253440000);               // 40960 B
  int* cur_  = (int*)(base + 253480960);               // 40960 B
  int* inv_  = (int*)(base + 253521920);               // 640000 B
  int* dst_s = (int*)(base + 254161920);               // 640000 B
  _Float16* W0fl = (_Float16*)(base + 254801920);      // 32768 B
  _Float16* W1fl = (_Float16*)(base + 254834688);      // 65536 B
  _Float16* W2fl = (_Float16*)(base + 254900224);      // 196608 B
  int*      perm = (int*)(base + 255096832);           // 40000 B
  _Float16* Wtfl = (_Float16*)(base + 255136832);      // 196608 B (Wt0..Wt5)
  int*      eid_s = (int*)(base + 255333440);          // 640000 B

  (void)in_sizes; (void)n_in; (void)out_size;

  // prep: weight packs + cur_ zeroing (one launch), then CSR chain
  k_prep<<<120, 256, 0, stream>>>(Wp, Ws1, Ws2, Wt0, Wt1, Wt2, Wt3, Wt4, Wt5,
                                  W0fl, W1fl, W2fl, Wtfl, cur_);
  k_hist<<<625, 256, 0, stream>>>(eidx, cur_);
  k_scan_sort<<<1, 1024, 0, stream>>>(cur_, off_, cur_, perm);
  k_scatter<<<625, 256, 0, stream>>>(eidx, eidx + EE, cur_, inv_, dst_s, eid_s);
  // per-node dst-sort (rewrites dst_s sorted + inv to match) - before G3/msgbr
  k_dstsort<<<2500, 256, 0, stream>>>(off_, dst_s, eid_s, inv_);

  // node phase: pack -> pipelined MFMA GEMM (M=90000,K=128,N=128) -> norm/decompose
  k_node_pre<<<2500, 256, 0, stream>>>(X, Xt);
  k_gemm_pipe<128, false, false, false><<<704, 256, 0, stream>>>(
      Xt, 128, W0fl, bp, nullptr, nullptr, Xp, 128, 9*NN, 1);
  k_node_post<<<5000, 256, 0, stream>>>(Xp, Xn, D1);

  // T' = clin(I,Wt0)/clin(A,Wt1)/clin(S,Wt2): 10 slices, pipelined PSEL
  k_gemm_pipe<128, false, false, true><<<dim3(79, 1, 10), 256, 0, stream>>>(
      (_Float16*)D1, 1280, Wtfl, nullptr, nullptr, nullptr,
      (_Float16*)T1, 1280, NN, 1);

  // edge MLP: layer1 (mfma, f32 A), layers 2-3 pipelined; G3 writes CSR-ordered
  k_gemm_mfma<float, 32, true><<<dim3(1250, 1, 1), 256, 0, stream>>>(
      eattr, 32, Ws0, bs0, (_Float16*)h0, 128, EE, 2);
  k_gemm_pipe<128, true, false, false><<<2500, 256, 0, stream>>>(
      (_Float16*)h0, 128, W1fl, bs1, nullptr, nullptr, (_Float16*)h1, 256, EE, 2);
  k_gemm_pipe<256, true, true, false><<<3750, 256, 0, stream>>>(
      (_Float16*)h1, 256, W2fl, bs2, ew, inv_, (_Float16*)ea, 384, EE, 3);

  // fused message + bracket (degree-balanced, dst-ordered): D2 -> region C
  k_msgbr<<<2500, 256, 0, stream>>>(ea, T1, dst_s, off_, perm, D2);

  // dX components = clin with Wt3/4/5 (pipelined PSEL; reads D2, writes Tb)
  k_gemm_pipe<128, false, false, true><<<dim3(79, 1, 10), 256, 0, stream>>>(
      (_Float16*)D2, 1280, Wtfl + 3*16384, nullptr, nullptr, nullptr,
      (_Float16*)Tb, 1280, NN, 1);

  // out = Xn + reconstruct(dX)
  k_final<<<5000, 256, 0, stream>>>(Xn, Tb, out);
}

// Round 14
// 357.369 us; speedup vs baseline: 1.0053x; 1.0053x over previous
//
#include <hip/hip_runtime.h>
#include <hip/hip_fp16.h>
#include <type_traits>

#define NN 10000
#define EE 160000

typedef _Float16 half8 __attribute__((ext_vector_type(8)));
typedef float    f32x4 __attribute__((ext_vector_type(4)));

// ---------------------------------------------------------------------------
// Node phase:
//  pre : Xt[(n,ij)][c] fp16  <- X[n][c][ij] f32      (pack/transpose)
//  gemm: Xp[(n,ij)][o] = sum_c Xt * Wp[o][c] + bp[o] (k_gemm_pipe)
//  post: per (n,o): norm over 9 ij, decompose -> Xn[n][o][ij], D1[n][10][128]
// ---------------------------------------------------------------------------
__global__ __launch_bounds__(256) void k_node_pre(
    const float* __restrict__ X, _Float16* __restrict__ Xt)
{
  __shared__ float Xl[4*1152];
  const int n0 = blockIdx.x * 4;
  const int t = threadIdx.x;
  const float* src = X + (size_t)n0*1152;
  #pragma unroll
  for (int idx = t; idx < 4*1152; idx += 256) Xl[idx] = src[idx];
  __syncthreads();
  _Float16* dst = Xt + (size_t)n0*1152;
  #pragma unroll
  for (int idx = t; idx < 4*1152; idx += 256) {
    int node = idx / 1152, rem = idx - node*1152;
    int ij = rem >> 7, c = rem & 127;
    dst[idx] = (_Float16)Xl[node*1152 + c*9 + ij];   // stride-9 LDS: odd -> conflict-free
  }
}

__global__ __launch_bounds__(256) void k_node_post(
    const _Float16* __restrict__ Xp,
    __half* __restrict__ Xn, __half* __restrict__ D1)
{
  int idx = blockIdx.x*256 + threadIdx.x;
  int n = idx >> 7, o = idx & 127;
  float m[9], ss = 0.f;
  #pragma unroll
  for (int ij = 0; ij < 9; ++ij) {
    m[ij] = (float)Xp[((size_t)n*9 + ij)*128 + o];   // coalesced across o
    ss += m[ij]*m[ij];
  }
  ss = fmaxf(ss, 0.01f);
  float inv = 1.f / (ss + 1.f);
  #pragma unroll
  for (int ij = 0; ij < 9; ++ij) m[ij] *= inv;
  __half* xo = &Xn[(size_t)n*1152 + o*9];
  #pragma unroll
  for (int ij = 0; ij < 9; ++ij) xo[ij] = __float2half(m[ij]);
  float lam = (m[0]+m[4]+m[8]) * (1.f/3.f);
  __half* Dn = &D1[(size_t)n*1280];
  Dn[0*128+o] = __float2half(lam);
  Dn[1*128+o] = __float2half(0.5f*(m[1]-m[3]));
  Dn[2*128+o] = __float2half(0.5f*(m[2]-m[6]));
  Dn[3*128+o] = __float2half(0.5f*(m[5]-m[7]));
  Dn[4*128+o] = __float2half(m[0]-lam);
  Dn[5*128+o] = __float2half(0.5f*(m[1]+m[3]));
  Dn[6*128+o] = __float2half(0.5f*(m[2]+m[6]));
  Dn[7*128+o] = __float2half(m[4]-lam);
  Dn[8*128+o] = __float2half(0.5f*(m[5]+m[7]));
  Dn[9*128+o] = __float2half(m[8]-lam);
}

// ---------------------------------------------------------------------------
// Prep (ONE launch): frag-linear fp16 pack of Wp, Ws1, Ws2, Wt0..Wt5 + zero cur_
//   Wfl[((kc*(N/16) + nf)*64 + lane)*8 + j] = W[nf*16+(lane&15)][kc*32+(lane>>4)*8+j]
// ---------------------------------------------------------------------------
__device__ __forceinline__ void wprep_one(
    const float* __restrict__ W, _Float16* __restrict__ Wfl, int N, int K, int u)
{
  int lane = u & 63, rest = u >> 6;
  int nfTotal = N >> 4;
  int nf = rest % nfTotal, kc = rest / nfTotal;
  int n = nf*16 + (lane & 15);
  int k = kc*32 + (lane >> 4)*8;
  const float* src = W + (size_t)n*K + k;
  half8 hv;
  #pragma unroll
  for (int j = 0; j < 8; ++j) hv[j] = (_Float16)src[j];
  *reinterpret_cast<half8*>(Wfl + (size_t)u*8) = hv;
}
__global__ __launch_bounds__(256) void k_prep(
    const float* __restrict__ Wp, const float* __restrict__ Ws1,
    const float* __restrict__ Ws2,
    const float* __restrict__ Wt0, const float* __restrict__ Wt1,
    const float* __restrict__ Wt2, const float* __restrict__ Wt3,
    const float* __restrict__ Wt4, const float* __restrict__ Wt5,
    _Float16* __restrict__ W0fl, _Float16* __restrict__ W1fl,
    _Float16* __restrict__ W2fl, _Float16* __restrict__ Wtfl,
    int* __restrict__ cur)
{
  int u = blockIdx.x*256 + threadIdx.x;
  if (u < NN) cur[u] = 0;
  if (u < 2048)        wprep_one(Wp,  W0fl, 128, 128, u);
  else if (u < 6144)   wprep_one(Ws1, W1fl, 256, 128, u - 2048);
  else if (u < 18432)  wprep_one(Ws2, W2fl, 384, 256, u - 6144);
  else if (u < 30720) {
    int v = u - 18432;
    int wi = v >> 11, r = v & 2047;
    const float* Wt = (wi==0)?Wt0:(wi==1)?Wt1:(wi==2)?Wt2:(wi==3)?Wt3:(wi==4)?Wt4:Wt5;
    wprep_one(Wt, Wtfl + wi*16384, 128, 128, r);
  }
}

// ---------------------------------------------------------------------------
// Pipelined MFMA GEMM (m97 structure): C[m][n] = post(sum_k A[m][k]*W[n][k]+b[n])
//   - BM=128, BN=128, BK=32, 4 waves; wave owns 32 rows x 128 cols (acc[2][8])
//   - A and W double-buffered via global_load_lds width-16 DMA (unified smem)
//   - A LDS seg pre-swizzled seg^(row&3) at source; read seg = lq^(lr&3)
//   - LDS-STAGED EPILOGUE (r14): fragments -> smem [128][128] tile -> 16B
//     coalesced row stores (64 scalar b16 stores/thread -> 8 b128 stores)
//   - rowmap (optional): output row permutation (CSR-ordered write)
//   - PSEL: blockIdx.z = p in 0..9: W = Wfl + widx*16384, A,C col-offset p*128
// ---------------------------------------------------------------------------
template<int KT, bool ACT, bool CUT, bool PSEL>
__global__ __launch_bounds__(256, 4) void k_gemm_pipe(
    const _Float16* __restrict__ A, int lda,
    const _Float16* __restrict__ Wfl,
    const float* __restrict__ bias, const float* __restrict__ cw,
    const int* __restrict__ rowmap,
    _Float16* __restrict__ C, int ldc,
    int M, int nTiles)
{
  constexpr int NC = KT / 32;
  __shared__ _Float16 smem[16384];   // A dbuf [0,8192) | W dbuf [8192,16384); epilogue: [128][128]
  const int t = threadIdx.x;
  const int nfTotal = nTiles * 8;

  int nwg = gridDim.x, bid = blockIdx.x;
  int q = nwg >> 3, rr = nwg & 7;
  int xcd = bid & 7, ii = bid >> 3;
  int swz = (xcd < rr) ? xcd*(q+1) + ii : rr*(q+1) + (xcd-rr)*q + ii;
  int nt = swz % nTiles, mt = swz / nTiles;
  const int n0 = nt * 128, m0 = mt * 128;

  const _Float16* Wb_ = Wfl;
  int coff = 0;
  if (PSEL) {
    int p = blockIdx.z;
    int widx = (p == 0) ? 0 : (p < 4 ? 1 : 2);
    Wb_ = Wfl + widx*16384;
    coff = p * 128;
  }

  auto stage = [&](int d, int kc) {
    #pragma unroll
    for (int i = 0; i < 2; ++i) {
      int u = t + i*256;
      int row = u >> 2, seg = u & 3;
      int gm = m0 + row; if (gm > M-1) gm = M-1;
      const _Float16* gp = A + (size_t)gm*lda + coff + kc*32 + ((seg ^ (row & 3)) << 3);
      __builtin_amdgcn_global_load_lds(
          (const __attribute__((address_space(1))) _Float16*)gp,
          (__attribute__((address_space(3))) _Float16*)(&smem[d*4096 + u*8]), 16, 0, 0);
    }
    const _Float16* wp = Wb_ + (((size_t)kc*nfTotal + nt*8) << 9);
    #pragma unroll
    for (int i = 0; i < 2; ++i) {
      int u = t + i*256;
      __builtin_amdgcn_global_load_lds(
          (const __attribute__((address_space(1))) _Float16*)(wp + u*8),
          (__attribute__((address_space(3))) _Float16*)(&smem[8192 + d*4096 + u*8]), 16, 0, 0);
    }
  };

  const int wave = t >> 6, lane = t & 63;
  const int lr = lane & 15, lq = lane >> 4;
  const int wrow = wave * 32;
  const int aoff = (lq ^ (lr & 3)) << 3;

  f32x4 acc[2][8] = {};

  stage(0, 0);
  __syncthreads();
  int cur = 0;
  for (int kc = 0; kc < NC; ++kc) {
    if (kc + 1 < NC) stage(cur ^ 1, kc + 1);
    const _Float16* ab = &smem[cur*4096];
    const _Float16* wb = &smem[8192 + cur*4096];
    half8 a0 = *reinterpret_cast<const half8*>(ab + (wrow + lr)*32 + aoff);
    half8 a1 = *reinterpret_cast<const half8*>(ab + (wrow + 16 + lr)*32 + aoff);
    #pragma unroll
    for (int c = 0; c < 8; ++c) {
      half8 b = *reinterpret_cast<const half8*>(wb + c*512 + lane*8);
      acc[0][c] = __builtin_amdgcn_mfma_f32_16x16x32_f16(a0, b, acc[0][c], 0, 0, 0);
      acc[1][c] = __builtin_amdgcn_mfma_f32_16x16x32_f16(a1, b, acc[1][c], 0, 0, 0);
    }
    if (kc + 1 < NC) { __syncthreads(); cur ^= 1; }
  }

  float bvv[8];
  #pragma unroll
  for (int c = 0; c < 8; ++c) bvv[c] = bias ? bias[n0 + c*16 + lr] : 0.f;

  // ---- epilogue phase 1: value compute + stage C tile [128][128] into smem
  __syncthreads();   // all MFMA LDS reads done before overwrite
  #pragma unroll
  for (int r = 0; r < 2; ++r) {
    #pragma unroll
    for (int j = 0; j < 4; ++j) {
      int lrow = wrow + r*16 + lq*4 + j;   // C/D: col=lane&15, row=(lane>>4)*4+reg
      float Cf = 1.f;
      if (CUT) {
        int gm = m0 + lrow; if (gm > M-1) gm = M-1;
        float wv = cw[gm];
        Cf = (wv < 5.f) ? 0.5f*(__cosf(wv*0.62831853071795864769f) + 1.f) : 0.f;
      }
      #pragma unroll
      for (int c = 0; c < 8; ++c) {
        float v = acc[r][c][j] + bvv[c];
        if (ACT) v = v / (1.f + __expf(-v));   // silu
        if (CUT) v *= Cf;
        smem[lrow*128 + c*16 + lr] = (_Float16)v;
      }
    }
  }
  __syncthreads();
  // ---- epilogue phase 2: coalesced stores (16 lanes x 16B = 256B per row)
  #pragma unroll
  for (int i = 0; i < 8; ++i) {
    int u = t + i*256;              // 0..2047
    int lrow = u >> 4, seg = u & 15;
    int gm = m0 + lrow;
    if (gm < M) {
      int orow = rowmap ? rowmap[gm] : gm;
      half8 hv = *reinterpret_cast<const half8*>(&smem[lrow*128 + seg*8]);
      *reinterpret_cast<half8*>(C + (size_t)orow*ldc + coff + n0 + seg*8) = hv;
    }
  }
}

// ---------------------------------------------------------------------------
// MFMA GEMM (non-pipelined; used for G1: f32 A, K=32):
//   BM=256, BN=64; W staged fp32->fp16 fragment-linear LDS (conflict-free)
// ---------------------------------------------------------------------------
template<typename TA, int KT, bool ACT>
__global__ __launch_bounds__(256) void k_gemm_mfma(
    const TA* __restrict__ A, int lda,
    const float* __restrict__ W0,
    const float* __restrict__ bias,
    _Float16* __restrict__ C, int ldc,
    int M, int nTiles)
{
  constexpr int NFRAG = (KT/32)*4;
  __shared__ _Float16 Bs[NFRAG*64*8];
  const int t = threadIdx.x;

  int nwg = gridDim.x;
  int bid = blockIdx.x;
  int q = nwg >> 3, rr = nwg & 7;
  int xcd = bid & 7, ii = bid >> 3;
  int swz = (xcd < rr) ? xcd*(q+1) + ii : rr*(q+1) + (xcd-rr)*q + ii;
  int nt = swz % nTiles;
  int mt = swz / nTiles;

  const float* W = W0;
  const int n0 = nt * 64;
  const int m0 = mt * 256;

  #pragma unroll
  for (int u = t; u < NFRAG*64; u += 256) {
    int g = u >> 6, lu = u & 63;
    int lru = lu & 15, lqu = lu >> 4;
    int nn = (g & 3)*16 + lru;
    int kk = (g >> 2)*32 + lqu*8;
    const float* wp = &W[(size_t)(n0 + nn)*KT + kk];
    f32x4 w0 = *reinterpret_cast<const f32x4*>(wp);
    f32x4 w1 = *reinterpret_cast<const f32x4*>(wp + 4);
    half8 hv;
    #pragma unroll
    for (int j = 0; j < 4; ++j) { hv[j] = (_Float16)w0[j]; hv[4+j] = (_Float16)w1[j]; }
    *reinterpret_cast<half8*>(&Bs[u*8]) = hv;
  }
  __syncthreads();

  const int wave = t >> 6, lane = t & 63;
  const int lr = lane & 15, lq = lane >> 4;
  const int rowBase = m0 + wave*64;
  const int kBase = lq*8;

  const TA* aptr[4];
  #pragma unroll
  for (int r = 0; r < 4; ++r) {
    int gm = rowBase + r*16 + lr;
    if (gm > M-1) gm = M-1;
    aptr[r] = A + (size_t)gm*lda + kBase;
  }

  f32x4 acc[4][4] = {};
  #pragma unroll
  for (int k0 = 0; k0 < KT; k0 += 32) {
    half8 b[4];
    #pragma unroll
    for (int c = 0; c < 4; ++c)
      b[c] = *reinterpret_cast<const half8*>(&Bs[(((k0>>5)<<2) + c)*512 + lane*8]);
    half8 a[4];
    #pragma unroll
    for (int r = 0; r < 4; ++r) {
      const TA* ap = aptr[r] + k0;
      if constexpr (std::is_same<TA, float>::value) {
        f32x4 u0 = *reinterpret_cast<const f32x4*>(ap);
        f32x4 u1 = *reinterpret_cast<const f32x4*>(ap + 4);
        half8 av;
        #pragma unroll
        for (int j = 0; j < 4; ++j) { av[j] = (_Float16)u0[j]; av[4+j] = (_Float16)u1[j]; }
        a[r] = av;
      } else {
        a[r] = *reinterpret_cast<const half8*>(ap);
      }
    }
    #pragma unroll
    for (int r = 0; r < 4; ++r)
      #pragma unroll
      for (int c = 0; c < 4; ++c)
        acc[r][c] = __builtin_amdgcn_mfma_f32_16x16x32_f16(a[r], b[c], acc[r][c], 0, 0, 0);
  }

  float bvv[4];
  #pragma unroll
  for (int c = 0; c < 4; ++c)
    bvv[c] = bias ? bias[n0 + c*16 + lr] : 0.f;
  #pragma unroll
  for (int r = 0; r < 4; ++r) {
    #pragma unroll
    for (int j = 0; j < 4; ++j) {
      int gm = rowBase + r*16 + lq*4 + j;
      if (gm >= M) continue;
      _Float16* crow = C + (size_t)gm*ldc + n0;
      #pragma unroll
      for (int c = 0; c < 4; ++c) {
        float v = acc[r][c][j] + bvv[c];
        if (ACT) v = v / (1.f + __expf(-v));
        crow[c*16 + lr] = (_Float16)v;
      }
    }
  }
}

// ---------------------------------------------------------------------------
// CSR build over src. Scatter emits inv[e]=pos and dst_s[pos]=dst[e].
// ---------------------------------------------------------------------------
__global__ void k_hist(const int* __restrict__ src, int* __restrict__ cnt) {
  int e = blockIdx.x*256 + threadIdx.x;
  if (e < EE) atomicAdd(&cnt[src[e]], 1);
}
// scan + degree-descending counting sort (both single-block -> merged)
__global__ __launch_bounds__(1024) void k_scan_sort(
    const int* __restrict__ cnt, int* __restrict__ off,
    int* __restrict__ cur, int* __restrict__ perm)
{
  __shared__ int s[1024];
  __shared__ int carry;
  __shared__ int bins[64];
  __shared__ int basep[64];
  int t = threadIdx.x;
  if (t == 0) carry = 0;
  __syncthreads();
  for (int base = 0; base < NN; base += 1024) {
    int i = base + t;
    int v = (i < NN) ? cnt[i] : 0;
    s[t] = v; __syncthreads();
    for (int d = 1; d < 1024; d <<= 1) {
      int x = (t >= d) ? s[t-d] : 0; __syncthreads();
      s[t] += x; __syncthreads();
    }
    int incl = s[t];
    int total = s[1023];
    int excl = incl - v + carry;
    if (i < NN) { off[i] = excl; cur[i] = excl; }
    __syncthreads();
    if (t == 0) carry += total;
    __syncthreads();
  }
  if (t == 0) off[NN] = carry;
  if (t < 64) bins[t] = 0;
  __syncthreads();
  for (int i = t; i < NN; i += 1024) {
    int d = off[i+1] - off[i];
    int b = 63 - (d > 63 ? 63 : d);
    atomicAdd(&bins[b], 1);
  }
  __syncthreads();
  if (t == 0) {
    int acc = 0;
    for (int b = 0; b < 64; ++b) { basep[b] = acc; acc += bins[b]; }
  }
  __syncthreads();
  for (int i = t; i < NN; i += 1024) {
    int d = off[i+1] - off[i];
    int b = 63 - (d > 63 ? 63 : d);
    int pos = atomicAdd(&basep[b], 1);
    perm[pos] = i;
  }
}
__global__ void k_scatter(const int* __restrict__ src, const int* __restrict__ dst,
                          int* __restrict__ cur,
                          int* __restrict__ inv, int* __restrict__ dst_s) {
  int e = blockIdx.x*256 + threadIdx.x;
  if (e < EE) {
    int pos = atomicAdd(&cur[src[e]], 1);
    inv[e] = pos;
    dst_s[pos] = dst[e];
  }
}

// ---------------------------------------------------------------------------
// Fused message + bracket, degree-balanced, dst-prefetched:
//  - 4 nodes/block via perm, 1 wave/node, lane l owns o-pair (2l, 2l+1)
//  - dst indices batch-prefetched (wave-load + v_readlane)
//  - msg in regs (f32); then B = M*Y+Y*M, decompose, /(tnorm+1)
//  - ea stream non-temporal; D2 buffer != T1
// ---------------------------------------------------------------------------
__device__ __forceinline__ void bracket10(
    const float* __restrict__ M, const float* __restrict__ Y,
    float* __restrict__ D)
{
  float Mm[9], Ym[9];
  Mm[0]=M[0]+M[4]; Mm[1]=M[1]+M[5]; Mm[2]=M[2]+M[6];
  Mm[3]=M[5]-M[1]; Mm[4]=M[0]+M[7]; Mm[5]=M[3]+M[8];
  Mm[6]=M[6]-M[2]; Mm[7]=M[8]-M[3]; Mm[8]=M[0]+M[9];
  Ym[0]=Y[0]+Y[4]; Ym[1]=Y[1]+Y[5]; Ym[2]=Y[2]+Y[6];
  Ym[3]=Y[5]-Y[1]; Ym[4]=Y[0]+Y[7]; Ym[5]=Y[3]+Y[8];
  Ym[6]=Y[6]-Y[2]; Ym[7]=Y[8]-Y[3]; Ym[8]=Y[0]+Y[9];
  float B[9];
  #pragma unroll
  for (int i = 0; i < 3; ++i)
    #pragma unroll
    for (int j = 0; j < 3; ++j) {
      float s = 0.f;
      #pragma unroll
      for (int k = 0; k < 3; ++k)
        s += Mm[i*3+k]*Ym[k*3+j] + Ym[i*3+k]*Mm[k*3+j];
      B[i*3+j] = s;
    }
  float lamb = (B[0]+B[4]+B[8]) * (1.f/3.f);
  float ss = 0.f;
  #pragma unroll
  for (int qq = 0; qq < 9; ++qq) ss += B[qq]*B[qq];
  float inv = 1.f / (fmaxf(ss, 0.01f) + 1.f);
  D[0] = lamb*inv;
  D[1] = 0.5f*(B[1]-B[3])*inv;
  D[2] = 0.5f*(B[2]-B[6])*inv;
  D[3] = 0.5f*(B[5]-B[7])*inv;
  D[4] = (B[0]-lamb)*inv;
  D[5] = 0.5f*(B[1]+B[3])*inv;
  D[6] = 0.5f*(B[2]+B[6])*inv;
  D[7] = (B[4]-lamb)*inv;
  D[8] = 0.5f*(B[5]+B[7])*inv;
  D[9] = (B[8]-lamb)*inv;
}

__device__ __forceinline__ float2 ld_nt_h2(const void* p) {
  unsigned int u = __builtin_nontemporal_load((const unsigned int*)p);
  return __half22float2(__builtin_bit_cast(__half2, u));
}

__global__ __launch_bounds__(256) void k_msgbr(
    const __half* __restrict__ ea_s, const __half* __restrict__ T1,
    const int* __restrict__ dst_s, const int* __restrict__ off,
    const int* __restrict__ perm, __half* __restrict__ D2)
{
  const int t = threadIdx.x;
  const int l = t & 63;
  const int wv = __builtin_amdgcn_readfirstlane(t >> 6);
  const int n = __builtin_amdgcn_readfirstlane(perm[blockIdx.x*4 + wv]);
  const int e0 = __builtin_amdgcn_readfirstlane(off[n]);
  const int e1 = __builtin_amdgcn_readfirstlane(off[n+1]);

  float a0[10] = {}, a1[10] = {};   // msg for o0=2l and o1=2l+1

  for (int be = e0; be < e1; be += 64) {
    // batch-prefetch up to 64 dst indices: lane l holds dst of edge be+l
    int my = be + l; if (my > e1-1) my = e1-1;
    int vd = dst_s[my];
    int hi = (be + 64 < e1) ? be + 64 : e1;

    auto edge = [&](int ii) {
      int d = __builtin_amdgcn_readlane(vd, ii - be);   // uniform idx, no mem op
      const __half2* fe = (const __half2*)(ea_s + (size_t)ii*384 + 6*l);
      float2 q0 = ld_nt_h2(fe);       // f0(o0), f1(o0)
      float2 q1 = ld_nt_h2(fe + 1);   // f2(o0), f0(o1)
      float2 q2 = ld_nt_h2(fe + 2);   // f1(o1), f2(o1)
      const __half2* Td = (const __half2*)(T1 + (size_t)d*1280) + l;
      float2 tc;
      tc = __half22float2(Td[0]);    a0[0] += q0.x*tc.x; a1[0] += q1.y*tc.y;
      tc = __half22float2(Td[64]);   a0[1] += q0.y*tc.x; a1[1] += q2.x*tc.y;
      tc = __half22float2(Td[128]);  a0[2] += q0.y*tc.x; a1[2] += q2.x*tc.y;
      tc = __half22float2(Td[192]);  a0[3] += q0.y*tc.x; a1[3] += q2.x*tc.y;
      #pragma unroll
      for (int c = 4; c < 10; ++c) {
        tc = __half22float2(Td[c*64]);
        a0[c] += q1.x*tc.x; a1[c] += q2.y*tc.y;
      }
    };
    int ii = be;
    for (; ii + 4 <= hi; ii += 4) { edge(ii); edge(ii+1); edge(ii+2); edge(ii+3); }
    for (; ii < hi; ++ii) edge(ii);
  }

  // own node's Y row
  const __half2* Yd = (const __half2*)(T1 + (size_t)n*1280) + l;
  float y0[10], y1[10];
  #pragma unroll
  for (int c = 0; c < 10; ++c) {
    float2 yc = __half22float2(Yd[c*64]);
    y0[c] = yc.x; y1[c] = yc.y;
  }
  float d0[10], d1[10];
  bracket10(a0, y0, d0);
  bracket10(a1, y1, d1);
  __half2* Dn = (__half2*)(D2 + (size_t)n*1280) + l;
  #pragma unroll
  for (int c = 0; c < 10; ++c)
    Dn[c*64] = __floats2half2_rn(d0[c], d1[c]);
}

// ---------------------------------------------------------------------------
// Final: out = Xn + reconstruct(Tb)
// ---------------------------------------------------------------------------
__global__ __launch_bounds__(256) void k_final(
    const __half* __restrict__ Xn, const __half* __restrict__ Tb,
    float* __restrict__ out)
{
  int idx = blockIdx.x*256 + threadIdx.x;
  int n = idx >> 7, o = idx & 127;
  const __half* Tc = &Tb[(size_t)n*1280 + o];
  float lam=(float)Tc[0], a0=(float)Tc[128], a1=(float)Tc[256], a2=(float)Tc[384];
  float s00=(float)Tc[512], s01=(float)Tc[640], s02=(float)Tc[768];
  float s11=(float)Tc[896], s12=(float)Tc[1024], s22=(float)Tc[1152];
  const __half* xc = &Xn[(size_t)n*1152 + o*9];
  float* oc = &out[(size_t)n*1152 + o*9];
  oc[0] = (float)xc[0] + lam + s00;
  oc[1] = (float)xc[1] + a0  + s01;
  oc[2] = (float)xc[2] + a1  + s02;
  oc[3] = (float)xc[3] - a0  + s01;
  oc[4] = (float)xc[4] + lam + s11;
  oc[5] = (float)xc[5] + a2  + s12;
  oc[6] = (float)xc[6] - a1  + s02;
  oc[7] = (float)xc[7] - a2  + s12;
  oc[8] = (float)xc[8] + lam + s22;
}

// ---------------------------------------------------------------------------
extern "C" void kernel_launch(void* const* d_in, const int* in_sizes, int n_in,
                              void* d_out, int out_size, void* d_ws, size_t ws_size,
                              hipStream_t stream)
{
  const float* X     = (const float*)d_in[0];
  const float* ew    = (const float*)d_in[1];
  const float* eattr = (const float*)d_in[2];
  const float* Wp    = (const float*)d_in[3];
  const float* bp    = (const float*)d_in[4];
  const float* Ws0   = (const float*)d_in[5];
  const float* bs0   = (const float*)d_in[6];
  const float* Ws1   = (const float*)d_in[7];
  const float* bs1   = (const float*)d_in[8];
  const float* Ws2   = (const float*)d_in[9];
  const float* bs2   = (const float*)d_in[10];
  const int*   eidx  = (const int*)d_in[11];
  const float* Wt0   = (const float*)d_in[12];
  const float* Wt1   = (const float*)d_in[13];
  const float* Wt2   = (const float*)d_in[14];
  const float* Wt3   = (const float*)d_in[15];
  const float* Wt4   = (const float*)d_in[16];
  const float* Wt5   = (const float*)d_in[17];
  float* out = (float*)d_out;

  // Packed lifetime-aliased layout, peak 255,333,440 B:
  //  A [0,          23,040,000)  Xn fp16                  [node_post -> final]
  //  B [23,040,000, 48,640,000)  T1 fp16 [K2 -> msgbr] -> Tb [K4 -> final]
  //  C [48,640,000, 130,560,000) {D1 | Xt | Xp} -> h1 -> D2 [msgbr -> K4]
  //  D [130,560,000,253,440,000) h0 -> ea_s               (122.88 MB)
  //  csr [253,440,000, 254,801,920)  off, cur, inv, dst_s
  //  Wfl [254,801,920, 255,096,832)  frag-linear fp16 Wp, Ws1, Ws2
  //  perm [255,096,832, 255,136,832); Wtfl [255,136,832, 255,333,440)
  const size_t NEED = 255333440;
  if (ws_size < NEED) return;   // diagnostic: poison-fail instead of fault

  char* base = (char*)d_ws;
  __half*   Xn  = (__half*)(base);
  __half*   T1  = (__half*)(base + 23040000);
  __half*   Tb  = (__half*)(base + 23040000);          // reuses T1 (dead after msgbr)
  __half*   D1  = (__half*)(base + 48640000);          // 25.6 MB [node_post -> K2]
  _Float16* Xt  = (_Float16*)(base + 74240000);        // 23.04 MB [pre -> gemm]
  _Float16* Xp  = (_Float16*)(base + 97280000);        // 23.04 MB [gemm -> post]
  __half*   h1  = (__half*)(base + 48640000);
  __half*   D2  = (__half*)(base + 48640000);          // msgbr output [-> K4]
  __half*   h0  = (__half*)(base + 130560000);
  __half*   ea  = (__half*)(base + 130560000);
  int* off_  = (int*)(base + 253440000);               // 40960 B
  int* cur_  = (int*)(base + 253480960);               // 40960 B
  int* inv_  = (int*)(base + 253521920);               // 640000 B
  int* dst_s = (int*)(base + 254161920);               // 640000 B
  _Float16* W0fl = (_Float16*)(base + 254801920);      // 32768 B
  _Float16* W1fl = (_Float16*)(base + 254834688);      // 65536 B
  _Float16* W2fl = (_Float16*)(base + 254900224);      // 196608 B
  int*      perm = (int*)(base + 255096832);           // 40000 B
  _Float16* Wtfl = (_Float16*)(base + 255136832);      // 196608 B (Wt0..Wt5)

  (void)in_sizes; (void)n_in; (void)out_size;

  // prep: weight packs + cur_ zeroing (one launch), then CSR chain
  k_prep<<<120, 256, 0, stream>>>(Wp, Ws1, Ws2, Wt0, Wt1, Wt2, Wt3, Wt4, Wt5,
                                  W0fl, W1fl, W2fl, Wtfl, cur_);
  k_hist<<<625, 256, 0, stream>>>(eidx, cur_);
  k_scan_sort<<<1, 1024, 0, stream>>>(cur_, off_, cur_, perm);
  k_scatter<<<625, 256, 0, stream>>>(eidx, eidx + EE, cur_, inv_, dst_s);

  // node phase: pack -> pipelined MFMA GEMM (M=90000,K=128,N=128) -> norm/decompose
  k_node_pre<<<2500, 256, 0, stream>>>(X, Xt);
  k_gemm_pipe<128, false, false, false><<<704, 256, 0, stream>>>(
      Xt, 128, W0fl, bp, nullptr, nullptr, Xp, 128, 9*NN, 1);
  k_node_post<<<5000, 256, 0, stream>>>(Xp, Xn, D1);

  // T' = clin(I,Wt0)/clin(A,Wt1)/clin(S,Wt2): 10 slices, pipelined PSEL
  k_gemm_pipe<128, false, false, true><<<dim3(79, 1, 10), 256, 0, stream>>>(
      (_Float16*)D1, 1280, Wtfl, nullptr, nullptr, nullptr,
      (_Float16*)T1, 1280, NN, 1);

  // edge MLP: layer1 (mfma, f32 A), layers 2-3 pipelined; G3 writes CSR-ordered
  k_gemm_mfma<float, 32, true><<<dim3(1250, 1, 1), 256, 0, stream>>>(
      eattr, 32, Ws0, bs0, (_Float16*)h0, 128, EE, 2);
  k_gemm_pipe<128, true, false, false><<<2500, 256, 0, stream>>>(
      (_Float16*)h0, 128, W1fl, bs1, nullptr, nullptr, (_Float16*)h1, 256, EE, 2);
  k_gemm_pipe<256, true, true, false><<<3750, 256, 0, stream>>>(
      (_Float16*)h1, 256, W2fl, bs2, ew, inv_, (_Float16*)ea, 384, EE, 3);

  // fused message + bracket (degree-balanced): D2 -> region C
  k_msgbr<<<2500, 256, 0, stream>>>(ea, T1, dst_s, off_, perm, D2);

  // dX components = clin with Wt3/4/5 (pipelined PSEL; reads D2, writes Tb)
  k_gemm_pipe<128, false, false, true><<<dim3(79, 1, 10), 256, 0, stream>>>(
      (_Float16*)D2, 1280, Wtfl + 3*16384, nullptr, nullptr, nullptr,
      (_Float16*)Tb, 1280, NN, 1);

  // out = Xn + reconstruct(dX)
  k_final<<<5000, 256, 0, stream>>>(Xn, Tb, out);
}

// Round 15
// 335.107 us; speedup vs baseline: 1.0721x; 1.0664x over previous
//
#include <hip/hip_runtime.h>
#include <hip/hip_fp16.h>
#include <type_traits>

#define NN 10000
#define EE 160000

typedef _Float16 half8 __attribute__((ext_vector_type(8)));
typedef float    f32x4 __attribute__((ext_vector_type(4)));

__device__ __forceinline__ float silu_fast(float v) {
  return v * __builtin_amdgcn_rcpf(1.f + __expf(-v));
}

// ---------------------------------------------------------------------------
// Node phase:
//  pre : Xt[(n,ij)][c] fp16  <- X[n][c][ij] f32      (pack/transpose)
//  gemm: Xp[(n,ij)][o] = sum_c Xt * Wp[o][c] + bp[o] (k_gemm_pipe)
//  post: per (n,o): norm over 9 ij, decompose -> Xn[n][o][ij], D1[n][10][128]
// ---------------------------------------------------------------------------
__global__ __launch_bounds__(256) void k_node_pre(
    const float* __restrict__ X, _Float16* __restrict__ Xt)
{
  __shared__ float Xl[4*1152];
  const int n0 = blockIdx.x * 4;
  const int t = threadIdx.x;
  const float* src = X + (size_t)n0*1152;
  #pragma unroll
  for (int idx = t; idx < 4*1152; idx += 256) Xl[idx] = src[idx];
  __syncthreads();
  _Float16* dst = Xt + (size_t)n0*1152;
  #pragma unroll
  for (int idx = t; idx < 4*1152; idx += 256) {
    int node = idx / 1152, rem = idx - node*1152;
    int ij = rem >> 7, c = rem & 127;
    dst[idx] = (_Float16)Xl[node*1152 + c*9 + ij];   // stride-9 LDS: odd -> conflict-free
  }
}

__global__ __launch_bounds__(256) void k_node_post(
    const _Float16* __restrict__ Xp,
    __half* __restrict__ Xn, __half* __restrict__ D1)
{
  int idx = blockIdx.x*256 + threadIdx.x;
  int n = idx >> 7, o = idx & 127;
  float m[9], ss = 0.f;
  #pragma unroll
  for (int ij = 0; ij < 9; ++ij) {
    m[ij] = (float)Xp[((size_t)n*9 + ij)*128 + o];   // coalesced across o
    ss += m[ij]*m[ij];
  }
  ss = fmaxf(ss, 0.01f);
  float inv = 1.f / (ss + 1.f);
  #pragma unroll
  for (int ij = 0; ij < 9; ++ij) m[ij] *= inv;
  __half* xo = &Xn[(size_t)n*1152 + o*9];
  #pragma unroll
  for (int ij = 0; ij < 9; ++ij) xo[ij] = __float2half(m[ij]);
  float lam = (m[0]+m[4]+m[8]) * (1.f/3.f);
  __half* Dn = &D1[(size_t)n*1280];
  Dn[0*128+o] = __float2half(lam);
  Dn[1*128+o] = __float2half(0.5f*(m[1]-m[3]));
  Dn[2*128+o] = __float2half(0.5f*(m[2]-m[6]));
  Dn[3*128+o] = __float2half(0.5f*(m[5]-m[7]));
  Dn[4*128+o] = __float2half(m[0]-lam);
  Dn[5*128+o] = __float2half(0.5f*(m[1]+m[3]));
  Dn[6*128+o] = __float2half(0.5f*(m[2]+m[6]));
  Dn[7*128+o] = __float2half(m[4]-lam);
  Dn[8*128+o] = __float2half(0.5f*(m[5]+m[7]));
  Dn[9*128+o] = __float2half(m[8]-lam);
}

// ---------------------------------------------------------------------------
// Prep (ONE launch): frag-linear fp16 pack of Wp, Ws1, Ws2, Wt0..Wt5 + zero cur_
// ---------------------------------------------------------------------------
__device__ __forceinline__ void wprep_one(
    const float* __restrict__ W, _Float16* __restrict__ Wfl, int N, int K, int u)
{
  int lane = u & 63, rest = u >> 6;
  int nfTotal = N >> 4;
  int nf = rest % nfTotal, kc = rest / nfTotal;
  int n = nf*16 + (lane & 15);
  int k = kc*32 + (lane >> 4)*8;
  const float* src = W + (size_t)n*K + k;
  half8 hv;
  #pragma unroll
  for (int j = 0; j < 8; ++j) hv[j] = (_Float16)src[j];
  *reinterpret_cast<half8*>(Wfl + (size_t)u*8) = hv;
}
__global__ __launch_bounds__(256) void k_prep(
    const float* __restrict__ Wp, const float* __restrict__ Ws1,
    const float* __restrict__ Ws2,
    const float* __restrict__ Wt0, const float* __restrict__ Wt1,
    const float* __restrict__ Wt2, const float* __restrict__ Wt3,
    const float* __restrict__ Wt4, const float* __restrict__ Wt5,
    _Float16* __restrict__ W0fl, _Float16* __restrict__ W1fl,
    _Float16* __restrict__ W2fl, _Float16* __restrict__ Wtfl,
    int* __restrict__ cur)
{
  int u = blockIdx.x*256 + threadIdx.x;
  if (u < NN) cur[u] = 0;
  if (u < 2048)        wprep_one(Wp,  W0fl, 128, 128, u);
  else if (u < 6144)   wprep_one(Ws1, W1fl, 256, 128, u - 2048);
  else if (u < 18432)  wprep_one(Ws2, W2fl, 384, 256, u - 6144);
  else if (u < 30720) {
    int v = u - 18432;
    int wi = v >> 11, r = v & 2047;
    const float* Wt = (wi==0)?Wt0:(wi==1)?Wt1:(wi==2)?Wt2:(wi==3)?Wt3:(wi==4)?Wt4:Wt5;
    wprep_one(Wt, Wtfl + wi*16384, 128, 128, r);
  }
}

// ---------------------------------------------------------------------------
// Pipelined MFMA GEMM (m97 structure): C[m][n] = post(sum_k A[m][k]*W[n][k]+b[n])
//   - BM=128, BN=128, BK=32, 4 waves; wave owns 32 rows x 128 cols (acc[2][8])
//   - A and W double-buffered via global_load_lds width-16 DMA
//   - A LDS seg pre-swizzled seg^(row&3) at source; read seg = lq^(lr&3)
//   - rowmap (optional): output row permutation (CSR-ordered write)
//   - PSEL: blockIdx.z = p in 0..9: W = Wfl + widx*16384, A,C col-offset p*128
// ---------------------------------------------------------------------------
template<int KT, bool ACT, bool CUT, bool PSEL>
__global__ __launch_bounds__(256, 4) void k_gemm_pipe(
    const _Float16* __restrict__ A, int lda,
    const _Float16* __restrict__ Wfl,
    const float* __restrict__ bias, const float* __restrict__ cw,
    const int* __restrict__ rowmap,
    _Float16* __restrict__ C, int ldc,
    int M, int nTiles)
{
  constexpr int NC = KT / 32;
  __shared__ _Float16 Abuf[2][128*32];
  __shared__ _Float16 Wbuf[2][128*32];
  const int t = threadIdx.x;
  const int nfTotal = nTiles * 8;

  int nwg = gridDim.x, bid = blockIdx.x;
  int q = nwg >> 3, rr = nwg & 7;
  int xcd = bid & 7, ii = bid >> 3;
  int swz = (xcd < rr) ? xcd*(q+1) + ii : rr*(q+1) + (xcd-rr)*q + ii;
  int nt = swz % nTiles, mt = swz / nTiles;
  const int n0 = nt * 128, m0 = mt * 128;

  const _Float16* Wb_ = Wfl;
  int coff = 0;
  if (PSEL) {
    int p = blockIdx.z;
    int widx = (p == 0) ? 0 : (p < 4 ? 1 : 2);
    Wb_ = Wfl + widx*16384;
    coff = p * 128;
  }

  auto stage = [&](int d, int kc) {
    #pragma unroll
    for (int i = 0; i < 2; ++i) {
      int u = t + i*256;
      int row = u >> 2, seg = u & 3;
      int gm = m0 + row; if (gm > M-1) gm = M-1;
      const _Float16* gp = A + (size_t)gm*lda + coff + kc*32 + ((seg ^ (row & 3)) << 3);
      __builtin_amdgcn_global_load_lds(
          (const __attribute__((address_space(1))) _Float16*)gp,
          (__attribute__((address_space(3))) _Float16*)(&Abuf[d][u*8]), 16, 0, 0);
    }
    const _Float16* wp = Wb_ + (((size_t)kc*nfTotal + nt*8) << 9);
    #pragma unroll
    for (int i = 0; i < 2; ++i) {
      int u = t + i*256;
      __builtin_amdgcn_global_load_lds(
          (const __attribute__((address_space(1))) _Float16*)(wp + u*8),
          (__attribute__((address_space(3))) _Float16*)(&Wbuf[d][u*8]), 16, 0, 0);
    }
  };

  const int wave = t >> 6, lane = t & 63;
  const int lr = lane & 15, lq = lane >> 4;
  const int wrow = wave * 32;
  const int aoff = (lq ^ (lr & 3)) << 3;

  f32x4 acc[2][8] = {};

  stage(0, 0);
  __syncthreads();
  int cur = 0;
  for (int kc = 0; kc < NC; ++kc) {
    if (kc + 1 < NC) stage(cur ^ 1, kc + 1);
    const _Float16* ab = &Abuf[cur][0];
    const _Float16* wb = &Wbuf[cur][0];
    half8 a0 = *reinterpret_cast<const half8*>(ab + (wrow + lr)*32 + aoff);
    half8 a1 = *reinterpret_cast<const half8*>(ab + (wrow + 16 + lr)*32 + aoff);
    #pragma unroll
    for (int c = 0; c < 8; ++c) {
      half8 b = *reinterpret_cast<const half8*>(wb + c*512 + lane*8);
      acc[0][c] = __builtin_amdgcn_mfma_f32_16x16x32_f16(a0, b, acc[0][c], 0, 0, 0);
      acc[1][c] = __builtin_amdgcn_mfma_f32_16x16x32_f16(a1, b, acc[1][c], 0, 0, 0);
    }
    if (kc + 1 < NC) { __syncthreads(); cur ^= 1; }
  }

  float bvv[8];
  #pragma unroll
  for (int c = 0; c < 8; ++c) bvv[c] = bias ? bias[n0 + c*16 + lr] : 0.f;
  #pragma unroll
  for (int r = 0; r < 2; ++r) {
    #pragma unroll
    for (int j = 0; j < 4; ++j) {
      int gm = m0 + wrow + r*16 + lq*4 + j;   // C/D: col=lane&15, row=(lane>>4)*4+reg
      if (gm >= M) continue;
      float Cf = 1.f;
      if (CUT) {
        float wv = cw[gm];
        Cf = (wv < 5.f) ? 0.5f*(__cosf(wv*0.62831853071795864769f) + 1.f) : 0.f;
      }
      int orow = rowmap ? rowmap[gm] : gm;
      _Float16* crow = C + (size_t)orow*ldc + coff + n0;
      #pragma unroll
      for (int c = 0; c < 8; ++c) {
        float v = acc[r][c][j] + bvv[c];
        if (ACT) v = silu_fast(v);
        if (CUT) v *= Cf;
        crow[c*16 + lr] = (_Float16)v;
      }
    }
  }
}

// ---------------------------------------------------------------------------
// MFMA GEMM (non-pipelined; used for G1: f32 A, K=32):
//   BM=256, BN=64; W staged fp32->fp16 fragment-linear LDS (conflict-free)
// ---------------------------------------------------------------------------
template<typename TA, int KT, bool ACT>
__global__ __launch_bounds__(256) void k_gemm_mfma(
    const TA* __restrict__ A, int lda,
    const float* __restrict__ W0,
    const float* __restrict__ bias,
    _Float16* __restrict__ C, int ldc,
    int M, int nTiles)
{
  constexpr int NFRAG = (KT/32)*4;
  __shared__ _Float16 Bs[NFRAG*64*8];
  const int t = threadIdx.x;

  int nwg = gridDim.x;
  int bid = blockIdx.x;
  int q = nwg >> 3, rr = nwg & 7;
  int xcd = bid & 7, ii = bid >> 3;
  int swz = (xcd < rr) ? xcd*(q+1) + ii : rr*(q+1) + (xcd-rr)*q + ii;
  int nt = swz % nTiles;
  int mt = swz / nTiles;

  const float* W = W0;
  const int n0 = nt * 64;
  const int m0 = mt * 256;

  #pragma unroll
  for (int u = t; u < NFRAG*64; u += 256) {
    int g = u >> 6, lu = u & 63;
    int lru = lu & 15, lqu = lu >> 4;
    int nn = (g & 3)*16 + lru;
    int kk = (g >> 2)*32 + lqu*8;
    const float* wp = &W[(size_t)(n0 + nn)*KT + kk];
    f32x4 w0 = *reinterpret_cast<const f32x4*>(wp);
    f32x4 w1 = *reinterpret_cast<const f32x4*>(wp + 4);
    half8 hv;
    #pragma unroll
    for (int j = 0; j < 4; ++j) { hv[j] = (_Float16)w0[j]; hv[4+j] = (_Float16)w1[j]; }
    *reinterpret_cast<half8*>(&Bs[u*8]) = hv;
  }
  __syncthreads();

  const int wave = t >> 6, lane = t & 63;
  const int lr = lane & 15, lq = lane >> 4;
  const int rowBase = m0 + wave*64;
  const int kBase = lq*8;

  const TA* aptr[4];
  #pragma unroll
  for (int r = 0; r < 4; ++r) {
    int gm = rowBase + r*16 + lr;
    if (gm > M-1) gm = M-1;
    aptr[r] = A + (size_t)gm*lda + kBase;
  }

  f32x4 acc[4][4] = {};
  #pragma unroll
  for (int k0 = 0; k0 < KT; k0 += 32) {
    half8 b[4];
    #pragma unroll
    for (int c = 0; c < 4; ++c)
      b[c] = *reinterpret_cast<const half8*>(&Bs[(((k0>>5)<<2) + c)*512 + lane*8]);
    half8 a[4];
    #pragma unroll
    for (int r = 0; r < 4; ++r) {
      const TA* ap = aptr[r] + k0;
      if constexpr (std::is_same<TA, float>::value) {
        f32x4 u0 = *reinterpret_cast<const f32x4*>(ap);
        f32x4 u1 = *reinterpret_cast<const f32x4*>(ap + 4);
        half8 av;
        #pragma unroll
        for (int j = 0; j < 4; ++j) { av[j] = (_Float16)u0[j]; av[4+j] = (_Float16)u1[j]; }
        a[r] = av;
      } else {
        a[r] = *reinterpret_cast<const half8*>(ap);
      }
    }
    #pragma unroll
    for (int r = 0; r < 4; ++r)
      #pragma unroll
      for (int c = 0; c < 4; ++c)
        acc[r][c] = __builtin_amdgcn_mfma_f32_16x16x32_f16(a[r], b[c], acc[r][c], 0, 0, 0);
  }

  float bvv[4];
  #pragma unroll
  for (int c = 0; c < 4; ++c)
    bvv[c] = bias ? bias[n0 + c*16 + lr] : 0.f;
  #pragma unroll
  for (int r = 0; r < 4; ++r) {
    #pragma unroll
    for (int j = 0; j < 4; ++j) {
      int gm = rowBase + r*16 + lq*4 + j;
      if (gm >= M) continue;
      _Float16* crow = C + (size_t)gm*ldc + n0;
      #pragma unroll
      for (int c = 0; c < 4; ++c) {
        float v = acc[r][c][j] + bvv[c];
        if (ACT) v = silu_fast(v);
        crow[c*16 + lr] = (_Float16)v;
      }
    }
  }
}

// ---------------------------------------------------------------------------
// CSR build over src. Scatter emits inv[e]=pos and dst_s[pos]=dst[e].
// ---------------------------------------------------------------------------
__global__ void k_hist(const int* __restrict__ src, int* __restrict__ cnt) {
  int e = blockIdx.x*256 + threadIdx.x;
  if (e < EE) atomicAdd(&cnt[src[e]], 1);
}
// scan + degree-descending counting sort (both single-block -> merged)
__global__ __launch_bounds__(1024) void k_scan_sort(
    const int* __restrict__ cnt, int* __restrict__ off,
    int* __restrict__ cur, int* __restrict__ perm)
{
  __shared__ int s[1024];
  __shared__ int carry;
  __shared__ int bins[64];
  __shared__ int basep[64];
  int t = threadIdx.x;
  if (t == 0) carry = 0;
  __syncthreads();
  for (int base = 0; base < NN; base += 1024) {
    int i = base + t;
    int v = (i < NN) ? cnt[i] : 0;
    s[t] = v; __syncthreads();
    for (int d = 1; d < 1024; d <<= 1) {
      int x = (t >= d) ? s[t-d] : 0; __syncthreads();
      s[t] += x; __syncthreads();
    }
    int incl = s[t];
    int total = s[1023];
    int excl = incl - v + carry;
    if (i < NN) { off[i] = excl; cur[i] = excl; }
    __syncthreads();
    if (t == 0) carry += total;
    __syncthreads();
  }
  if (t == 0) off[NN] = carry;
  if (t < 64) bins[t] = 0;
  __syncthreads();
  for (int i = t; i < NN; i += 1024) {
    int d = off[i+1] - off[i];
    int b = 63 - (d > 63 ? 63 : d);
    atomicAdd(&bins[b], 1);
  }
  __syncthreads();
  if (t == 0) {
    int acc = 0;
    for (int b = 0; b < 64; ++b) { basep[b] = acc; acc += bins[b]; }
  }
  __syncthreads();
  for (int i = t; i < NN; i += 1024) {
    int d = off[i+1] - off[i];
    int b = 63 - (d > 63 ? 63 : d);
    int pos = atomicAdd(&basep[b], 1);
    perm[pos] = i;
  }
}
__global__ void k_scatter(const int* __restrict__ src, const int* __restrict__ dst,
                          int* __restrict__ cur,
                          int* __restrict__ inv, int* __restrict__ dst_s) {
  int e = blockIdx.x*256 + threadIdx.x;
  if (e < EE) {
    int pos = atomicAdd(&cur[src[e]], 1);
    inv[e] = pos;
    dst_s[pos] = dst[e];
  }
}

// ---------------------------------------------------------------------------
// Fused message + bracket, WAVE-SPLIT (2 waves/node):
//  - block = 4 waves = 2 nodes via perm; wave (ni,half) handles half the
//    node's CSR edge range; wave B dumps 20 f32 partials to LDS (pad 21);
//    wave A combines, brackets, stores. Halves per-wave latency chain and
//    doubles schedulable waves (tail fill).
//  - lane l owns o-pair (2l, 2l+1); dst batch-prefetch + v_readlane
//  - ea stream non-temporal; D2 buffer != T1
// ---------------------------------------------------------------------------
__device__ __forceinline__ void bracket10(
    const float* __restrict__ M, const float* __restrict__ Y,
    float* __restrict__ D)
{
  float Mm[9], Ym[9];
  Mm[0]=M[0]+M[4]; Mm[1]=M[1]+M[5]; Mm[2]=M[2]+M[6];
  Mm[3]=M[5]-M[1]; Mm[4]=M[0]+M[7]; Mm[5]=M[3]+M[8];
  Mm[6]=M[6]-M[2]; Mm[7]=M[8]-M[3]; Mm[8]=M[0]+M[9];
  Ym[0]=Y[0]+Y[4]; Ym[1]=Y[1]+Y[5]; Ym[2]=Y[2]+Y[6];
  Ym[3]=Y[5]-Y[1]; Ym[4]=Y[0]+Y[7]; Ym[5]=Y[3]+Y[8];
  Ym[6]=Y[6]-Y[2]; Ym[7]=Y[8]-Y[3]; Ym[8]=Y[0]+Y[9];
  float B[9];
  #pragma unroll
  for (int i = 0; i < 3; ++i)
    #pragma unroll
    for (int j = 0; j < 3; ++j) {
      float s = 0.f;
      #pragma unroll
      for (int k = 0; k < 3; ++k)
        s += Mm[i*3+k]*Ym[k*3+j] + Ym[i*3+k]*Mm[k*3+j];
      B[i*3+j] = s;
    }
  float lamb = (B[0]+B[4]+B[8]) * (1.f/3.f);
  float ss = 0.f;
  #pragma unroll
  for (int qq = 0; qq < 9; ++qq) ss += B[qq]*B[qq];
  float inv = 1.f / (fmaxf(ss, 0.01f) + 1.f);
  D[0] = lamb*inv;
  D[1] = 0.5f*(B[1]-B[3])*inv;
  D[2] = 0.5f*(B[2]-B[6])*inv;
  D[3] = 0.5f*(B[5]-B[7])*inv;
  D[4] = (B[0]-lamb)*inv;
  D[5] = 0.5f*(B[1]+B[3])*inv;
  D[6] = 0.5f*(B[2]+B[6])*inv;
  D[7] = (B[4]-lamb)*inv;
  D[8] = 0.5f*(B[5]+B[7])*inv;
  D[9] = (B[8]-lamb)*inv;
}

__device__ __forceinline__ float2 ld_nt_h2(const void* p) {
  unsigned int u = __builtin_nontemporal_load((const unsigned int*)p);
  return __half22float2(__builtin_bit_cast(__half2, u));
}

__global__ __launch_bounds__(256) void k_msgbr(
    const __half* __restrict__ ea_s, const __half* __restrict__ T1,
    const int* __restrict__ dst_s, const int* __restrict__ off,
    const int* __restrict__ perm, __half* __restrict__ D2)
{
  __shared__ float part[2][64][21];   // wave-B partials; pad 21 -> conflict-free
  const int t = threadIdx.x;
  const int l = t & 63;
  const int wv = __builtin_amdgcn_readfirstlane(t >> 6);
  const int ni = wv >> 1, half = wv & 1;
  const int n = __builtin_amdgcn_readfirstlane(perm[blockIdx.x*2 + ni]);
  const int E0 = __builtin_amdgcn_readfirstlane(off[n]);
  const int E1 = __builtin_amdgcn_readfirstlane(off[n+1]);
  const int mid = E0 + ((E1 - E0 + 1) >> 1);
  const int e0 = half ? mid : E0;
  const int e1 = half ? E1 : mid;

  float a0[10] = {}, a1[10] = {};   // msg for o0=2l and o1=2l+1

  for (int be = e0; be < e1; be += 64) {
    // batch-prefetch up to 64 dst indices: lane l holds dst of edge be+l
    int my = be + l; if (my > e1-1) my = e1-1;
    int vd = dst_s[my];
    int hi = (be + 64 < e1) ? be + 64 : e1;

    auto edge = [&](int ii) {
      int d = __builtin_amdgcn_readlane(vd, ii - be);   // uniform idx, no mem op
      const __half2* fe = (const __half2*)(ea_s + (size_t)ii*384 + 6*l);
      float2 q0 = ld_nt_h2(fe);       // f0(o0), f1(o0)
      float2 q1 = ld_nt_h2(fe + 1);   // f2(o0), f0(o1)
      float2 q2 = ld_nt_h2(fe + 2);   // f1(o1), f2(o1)
      const __half2* Td = (const __half2*)(T1 + (size_t)d*1280) + l;
      float2 tc;
      tc = __half22float2(Td[0]);    a0[0] += q0.x*tc.x; a1[0] += q1.y*tc.y;
      tc = __half22float2(Td[64]);   a0[1] += q0.y*tc.x; a1[1] += q2.x*tc.y;
      tc = __half22float2(Td[128]);  a0[2] += q0.y*tc.x; a1[2] += q2.x*tc.y;
      tc = __half22float2(Td[192]);  a0[3] += q0.y*tc.x; a1[3] += q2.x*tc.y;
      #pragma unroll
      for (int c = 4; c < 10; ++c) {
        tc = __half22float2(Td[c*64]);
        a0[c] += q1.x*tc.x; a1[c] += q2.y*tc.y;
      }
    };
    int ii = be;
    for (; ii + 4 <= hi; ii += 4) { edge(ii); edge(ii+1); edge(ii+2); edge(ii+3); }
    for (; ii < hi; ++ii) edge(ii);
  }

  if (half) {
    #pragma unroll
    for (int c = 0; c < 10; ++c) part[ni][l][c] = a0[c];
    #pragma unroll
    for (int c = 0; c < 10; ++c) part[ni][l][c+10] = a1[c];
  }
  __syncthreads();
  if (!half) {
    #pragma unroll
    for (int c = 0; c < 10; ++c) a0[c] += part[ni][l][c];
    #pragma unroll
    for (int c = 0; c < 10; ++c) a1[c] += part[ni][l][c+10];

    // own node's Y row
    const __half2* Yd = (const __half2*)(T1 + (size_t)n*1280) + l;
    float y0[10], y1[10];
    #pragma unroll
    for (int c = 0; c < 10; ++c) {
      float2 yc = __half22float2(Yd[c*64]);
      y0[c] = yc.x; y1[c] = yc.y;
    }
    float d0[10], d1[10];
    bracket10(a0, y0, d0);
    bracket10(a1, y1, d1);
    __half2* Dn = (__half2*)(D2 + (size_t)n*1280) + l;
    #pragma unroll
    for (int c = 0; c < 10; ++c)
      Dn[c*64] = __floats2half2_rn(d0[c], d1[c]);
  }
}

// ---------------------------------------------------------------------------
// Final: out = Xn + reconstruct(Tb)
// ---------------------------------------------------------------------------
__global__ __launch_bounds__(256) void k_final(
    const __half* __restrict__ Xn, const __half* __restrict__ Tb,
    float* __restrict__ out)
{
  int idx = blockIdx.x*256 + threadIdx.x;
  int n = idx >> 7, o = idx & 127;
  const __half* Tc = &Tb[(size_t)n*1280 + o];
  float lam=(float)Tc[0], a0=(float)Tc[128], a1=(float)Tc[256], a2=(float)Tc[384];
  float s00=(float)Tc[512], s01=(float)Tc[640], s02=(float)Tc[768];
  float s11=(float)Tc[896], s12=(float)Tc[1024], s22=(float)Tc[1152];
  const __half* xc = &Xn[(size_t)n*1152 + o*9];
  float* oc = &out[(size_t)n*1152 + o*9];
  oc[0] = (float)xc[0] + lam + s00;
  oc[1] = (float)xc[1] + a0  + s01;
  oc[2] = (float)xc[2] + a1  + s02;
  oc[3] = (float)xc[3] - a0  + s01;
  oc[4] = (float)xc[4] + lam + s11;
  oc[5] = (float)xc[5] + a2  + s12;
  oc[6] = (float)xc[6] - a1  + s02;
  oc[7] = (float)xc[7] - a2  + s12;
  oc[8] = (float)xc[8] + lam + s22;
}

// ---------------------------------------------------------------------------
extern "C" void kernel_launch(void* const* d_in, const int* in_sizes, int n_in,
                              void* d_out, int out_size, void* d_ws, size_t ws_size,
                              hipStream_t stream)
{
  const float* X     = (const float*)d_in[0];
  const float* ew    = (const float*)d_in[1];
  const float* eattr = (const float*)d_in[2];
  const float* Wp    = (const float*)d_in[3];
  const float* bp    = (const float*)d_in[4];
  const float* Ws0   = (const float*)d_in[5];
  const float* bs0   = (const float*)d_in[6];
  const float* Ws1   = (const float*)d_in[7];
  const float* bs1   = (const float*)d_in[8];
  const float* Ws2   = (const float*)d_in[9];
  const float* bs2   = (const float*)d_in[10];
  const int*   eidx  = (const int*)d_in[11];
  const float* Wt0   = (const float*)d_in[12];
  const float* Wt1   = (const float*)d_in[13];
  const float* Wt2   = (const float*)d_in[14];
  const float* Wt3   = (const float*)d_in[15];
  const float* Wt4   = (const float*)d_in[16];
  const float* Wt5   = (const float*)d_in[17];
  float* out = (float*)d_out;

  // Packed lifetime-aliased layout, peak 255,333,440 B:
  //  A [0,          23,040,000)  Xn fp16                  [node_post -> final]
  //  B [23,040,000, 48,640,000)  T1 fp16 [K2 -> msgbr] -> Tb [K4 -> final]
  //  C [48,640,000, 130,560,000) {D1 | Xt | Xp} -> h1 -> D2 [msgbr -> K4]
  //  D [130,560,000,253,440,000) h0 -> ea_s               (122.88 MB)
  //  csr [253,440,000, 254,801,920)  off, cur, inv, dst_s
  //  Wfl [254,801,920, 255,096,832)  frag-linear fp16 Wp, Ws1, Ws2
  //  perm [255,096,832, 255,136,832); Wtfl [255,136,832, 255,333,440)
  const size_t NEED = 255333440;
  if (ws_size < NEED) return;   // diagnostic: poison-fail instead of fault

  char* base = (char*)d_ws;
  __half*   Xn  = (__half*)(base);
  __half*   T1  = (__half*)(base + 23040000);
  __half*   Tb  = (__half*)(base + 23040000);          // reuses T1 (dead after msgbr)
  __half*   D1  = (__half*)(base + 48640000);          // 25.6 MB [node_post -> K2]
  _Float16* Xt  = (_Float16*)(base + 74240000);        // 23.04 MB [pre -> gemm]
  _Float16* Xp  = (_Float16*)(base + 97280000);        // 23.04 MB [gemm -> post]
  __half*   h1  = (__half*)(base + 48640000);
  __half*   D2  = (__half*)(base + 48640000);          // msgbr output [-> K4]
  __half*   h0  = (__half*)(base + 130560000);
  __half*   ea  = (__half*)(base + 130560000);
  int* off_  = (int*)(base + 253440000);               // 40960 B
  int* cur_  = (int*)(base + 253480960);               // 40960 B
  int* inv_  = (int*)(base + 253521920);               // 640000 B
  int* dst_s = (int*)(base + 254161920);               // 640000 B
  _Float16* W0fl = (_Float16*)(base + 254801920);      // 32768 B
  _Float16* W1fl = (_Float16*)(base + 254834688);      // 65536 B
  _Float16* W2fl = (_Float16*)(base + 254900224);      // 196608 B
  int*      perm = (int*)(base + 255096832);           // 40000 B
  _Float16* Wtfl = (_Float16*)(base + 255136832);      // 196608 B (Wt0..Wt5)

  (void)in_sizes; (void)n_in; (void)out_size;

  // prep: weight packs + cur_ zeroing (one launch), then CSR chain
  k_prep<<<120, 256, 0, stream>>>(Wp, Ws1, Ws2, Wt0, Wt1, Wt2, Wt3, Wt4, Wt5,
                                  W0fl, W1fl, W2fl, Wtfl, cur_);
  k_hist<<<625, 256, 0, stream>>>(eidx, cur_);
  k_scan_sort<<<1, 1024, 0, stream>>>(cur_, off_, cur_, perm);
  k_scatter<<<625, 256, 0, stream>>>(eidx, eidx + EE, cur_, inv_, dst_s);

  // node phase: pack -> pipelined MFMA GEMM (M=90000,K=128,N=128) -> norm/decompose
  k_node_pre<<<2500, 256, 0, stream>>>(X, Xt);
  k_gemm_pipe<128, false, false, false><<<704, 256, 0, stream>>>(
      Xt, 128, W0fl, bp, nullptr, nullptr, Xp, 128, 9*NN, 1);
  k_node_post<<<5000, 256, 0, stream>>>(Xp, Xn, D1);

  // T' = clin(I,Wt0)/clin(A,Wt1)/clin(S,Wt2): 10 slices, pipelined PSEL
  k_gemm_pipe<128, false, false, true><<<dim3(79, 1, 10), 256, 0, stream>>>(
      (_Float16*)D1, 1280, Wtfl, nullptr, nullptr, nullptr,
      (_Float16*)T1, 1280, NN, 1);

  // edge MLP: layer1 (mfma, f32 A), layers 2-3 pipelined; G3 writes CSR-ordered
  k_gemm_mfma<float, 32, true><<<dim3(1250, 1, 1), 256, 0, stream>>>(
      eattr, 32, Ws0, bs0, (_Float16*)h0, 128, EE, 2);
  k_gemm_pipe<128, true, false, false><<<2500, 256, 0, stream>>>(
      (_Float16*)h0, 128, W1fl, bs1, nullptr, nullptr, (_Float16*)h1, 256, EE, 2);
  k_gemm_pipe<256, true, true, false><<<3750, 256, 0, stream>>>(
      (_Float16*)h1, 256, W2fl, bs2, ew, inv_, (_Float16*)ea, 384, EE, 3);

  // fused message + bracket (wave-split, degree-balanced): D2 -> region C
  k_msgbr<<<5000, 256, 0, stream>>>(ea, T1, dst_s, off_, perm, D2);

  // dX components = clin with Wt3/4/5 (pipelined PSEL; reads D2, writes Tb)
  k_gemm_pipe<128, false, false, true><<<dim3(79, 1, 10), 256, 0, stream>>>(
      (_Float16*)D2, 1280, Wtfl + 3*16384, nullptr, nullptr, nullptr,
      (_Float16*)Tb, 1280, NN, 1);

  // out = Xn + reconstruct(dX)
  k_final<<<5000, 256, 0, stream>>>(Xn, Tb, out);
}